// Round 12
// baseline (3609.291 us; speedup 1.0000x reference)
//
#include <hip/hip_runtime.h>
#include <stdint.h>

// ImplicitQueryAttention: y <- softmax((x W_K^T) W_Q y^T) x, 10 iters.
// Ktil = (x W_K^T) W_Q is iteration-invariant -> precompute once.
// Per iter: scores = Ktil @ y^T (NT), row-softmax, y = P @ x (NT vs x^T).
//
// PRECISION (round-4 absmax 6.1 bf16; round-11 absmax 0.64 plain fp16-split):
// the iteration amplifies per-step score noise ~3x/iter; plain fp16-split's
// residual came from SUBNORMAL fp16 lo-parts (|lo|<2^-14 whenever |v|<0.25,
// ~20% of elements) flushed in the f16 MFMA path -> delta0 ~1.5e-4/iter.
// Fix: SCALED lo (lo' = (v-hi)*2^11, always fp16-normal) + separate
// correction accumulator: accM += ah*bh;  accC += ah*bl' + al'*bh;
// result = accM + accC*2^-11. Representation error back to 2^-22*|v| with
// no subnormal anywhere; residual noise = f32-accumulation class.
//
// Workspace (200 MB):
//   [0,16)    xh      [B*N, D] fp16     [16,32)   xl (scaled lo)
//   [32,48)   xTh     [B][D][N] fp16    [48,64)   xTl
//   [64,80)   ktilh   [B*N, D] fp16     [80,96)   ktill
//   [96,112)  yh      [B*N, D] fp16     [112,128) yl   (K hi/lo during prep)
//   [128,130) wkh  [130,132) wkl  [132,134) wqth  [134,136) wqtl
//   [136,200) scores [B][N][N] f32; after softmax each 8KB row holds
//             2048 fp16 P_hi | 2048 fp16 P_lo' (in-place, row-local).

#define DEVI __device__ __forceinline__

typedef _Float16 f16;
typedef __attribute__((ext_vector_type(8))) _Float16 half8;
typedef __attribute__((ext_vector_type(4))) _Float16 half4;
typedef __attribute__((ext_vector_type(4))) float f32x4;

#define LO_SCALE 2048.0f          // 2^11
#define LO_INV   4.8828125e-4f    // 2^-11, exact

DEVI void async_ld16(void* lds, const void* g) {
  __builtin_amdgcn_global_load_lds(
      (const __attribute__((address_space(1))) uint32_t*)g,
      (__attribute__((address_space(3))) uint32_t*)lds,
      16, 0, 0);
}

// C = (Ah + Al/2^11) @ (Bh + Bl/2^11)^T, f32 accum, 3-term split-fp16 MFMA
// with scaled-lo correction accumulator.
// A rows [M,K] stride lda; B rows [N,K] stride ldb (fp16 hi + scaled-lo).
// OUT=0: write f32 Cf. OUT=1: write fp16 hi / scaled-lo split to Ch, Cl.
// Batched via blockIdx.z with element strides sA, sB, sC.
template<int OUT>
__global__ __launch_bounds__(256)
void gemm3_nt(const f16* __restrict__ Ah, const f16* __restrict__ Al, int lda,
              const f16* __restrict__ Bh, const f16* __restrict__ Bl, int ldb,
              float* __restrict__ Cf, f16* __restrict__ Ch, f16* __restrict__ Cl,
              int ldc, int K, size_t sA, size_t sB, size_t sC)
{
  __shared__ f16 lAh[128][64];
  __shared__ f16 lAl[128][64];
  __shared__ f16 lBh[128][64];
  __shared__ f16 lBl[128][64];
  const int tid  = threadIdx.x;
  const int lane = tid & 63;
  const int wid  = tid >> 6;
  const int wr   = wid >> 1, wc = wid & 1;   // 2x2 wave grid, 64x64 each
  const int row0 = blockIdx.x * 128;
  const int col0 = blockIdx.y * 128;
  const size_t z = blockIdx.z;
  Ah += z * sA;  Al += z * sA;  Bh += z * sB;  Bl += z * sB;

  f32x4 accM[4][4];   // ah*bh
  f32x4 accC[4][4];   // ah*bl' + al'*bh  (scaled by 2^11)
  #pragma unroll
  for (int i = 0; i < 4; i++)
    #pragma unroll
    for (int j = 0; j < 4; j++) {
      accM[i][j] = f32x4{0.f, 0.f, 0.f, 0.f};
      accC[i][j] = f32x4{0.f, 0.f, 0.f, 0.f};
    }

  // Each wave stages 32 rows of each tile; one global_load_lds = 8 rows.
  const int srow = wid * 32 + (lane >> 3);
  const int scol = (lane & 7) * 8;
  const f16* gah = Ah + (size_t)(row0 + srow) * lda + scol;
  const f16* gal = Al + (size_t)(row0 + srow) * lda + scol;
  const f16* gbh = Bh + (size_t)(col0 + srow) * ldb + scol;
  const f16* gbl = Bl + (size_t)(col0 + srow) * ldb + scol;

  for (int kt = 0; kt < K; kt += 64) {
    __syncthreads();   // previous tile's ds_reads done before overwrite
    #pragma unroll
    for (int i = 0; i < 4; i++) {
      const size_t o = (size_t)i * 8;
      async_ld16(&lAh[wid * 32 + i * 8][0], gah + o * lda + kt);
      async_ld16(&lAl[wid * 32 + i * 8][0], gal + o * lda + kt);
      async_ld16(&lBh[wid * 32 + i * 8][0], gbh + o * ldb + kt);
      async_ld16(&lBl[wid * 32 + i * 8][0], gbl + o * ldb + kt);
    }
    __syncthreads();   // vmcnt(0) drain at barrier: tiles resident

    #pragma unroll
    for (int kk = 0; kk < 2; ++kk) {
      const int ks = kk * 32 + (lane >> 4) * 8;  // lane's k-chunk
      const int fr = lane & 15;                  // frag row/col
      half8 avh[4], avl[4], bvh[4], bvl[4];
      #pragma unroll
      for (int mi = 0; mi < 4; mi++) {
        avh[mi] = *(const half8*)&lAh[wr * 64 + mi * 16 + fr][ks];
        avl[mi] = *(const half8*)&lAl[wr * 64 + mi * 16 + fr][ks];
      }
      #pragma unroll
      for (int ni = 0; ni < 4; ni++) {
        bvh[ni] = *(const half8*)&lBh[wc * 64 + ni * 16 + fr][ks];
        bvl[ni] = *(const half8*)&lBl[wc * 64 + ni * 16 + fr][ks];
      }
      #pragma unroll
      for (int mi = 0; mi < 4; mi++)
        #pragma unroll
        for (int ni = 0; ni < 4; ni++) {
          accC[mi][ni] = __builtin_amdgcn_mfma_f32_16x16x32_f16(
              avh[mi], bvl[ni], accC[mi][ni], 0, 0, 0);
          accC[mi][ni] = __builtin_amdgcn_mfma_f32_16x16x32_f16(
              avl[mi], bvh[ni], accC[mi][ni], 0, 0, 0);
          accM[mi][ni] = __builtin_amdgcn_mfma_f32_16x16x32_f16(
              avh[mi], bvh[ni], accM[mi][ni], 0, 0, 0);
        }
    }
  }

  // C/D layout: col = lane&15, row = (lane>>4)*4 + reg  [m89/m91 verified]
  const int r4 = (lane >> 4) * 4;
  const int cc = lane & 15;
  #pragma unroll
  for (int mi = 0; mi < 4; mi++) {
    #pragma unroll
    for (int ni = 0; ni < 4; ni++) {
      #pragma unroll
      for (int k = 0; k < 4; k++) {
        const int row = row0 + wr * 64 + mi * 16 + r4 + k;
        const int col = col0 + wc * 64 + ni * 16 + cc;
        const float v = accM[mi][ni][k] + accC[mi][ni][k] * LO_INV;
        const size_t idx = z * sC + (size_t)row * ldc + col;
        if constexpr (OUT == 0) {
          Cf[idx] = v;
        } else {
          f16 h = (f16)v;
          f16 l = (f16)((v - (float)h) * LO_SCALE);  // exact residual, scaled
          Ch[idx] = h;
          Cl[idx] = l;
        }
      }
    }
  }
}

// One 256-thread block per 2048-f32 score row. In-place: row's 8KB becomes
// [2048 fp16 P_hi | 2048 fp16 P_lo']. Loads complete (data-dep) before the
// reduction barriers; stores after them -> no intra-row hazard.
__global__ __launch_bounds__(256)
void softmax_split(float* __restrict__ s) {
  const size_t row = blockIdx.x;
  float* sr = s + row * 2048;
  f16* pr = (f16*)sr;
  const int t = threadIdx.x;
  float4 v0 = *(const float4*)&sr[4 * t];
  float4 v1 = *(const float4*)&sr[4 * t + 1024];
  float m = fmaxf(fmaxf(fmaxf(v0.x, v0.y), fmaxf(v0.z, v0.w)),
                  fmaxf(fmaxf(v1.x, v1.y), fmaxf(v1.z, v1.w)));
  #pragma unroll
  for (int o = 32; o; o >>= 1) m = fmaxf(m, __shfl_xor(m, o));
  __shared__ float redm[4], reds[4];
  if ((t & 63) == 0) redm[t >> 6] = m;
  __syncthreads();
  m = fmaxf(fmaxf(redm[0], redm[1]), fmaxf(redm[2], redm[3]));
  float e[8];
  e[0] = expf(v0.x - m); e[1] = expf(v0.y - m);
  e[2] = expf(v0.z - m); e[3] = expf(v0.w - m);
  e[4] = expf(v1.x - m); e[5] = expf(v1.y - m);
  e[6] = expf(v1.z - m); e[7] = expf(v1.w - m);
  float sum = ((e[0] + e[1]) + (e[2] + e[3])) + ((e[4] + e[5]) + (e[6] + e[7]));
  #pragma unroll
  for (int o = 32; o; o >>= 1) sum += __shfl_xor(sum, o);
  if ((t & 63) == 0) reds[t >> 6] = sum;
  __syncthreads();
  const float inv = 1.f / ((reds[0] + reds[1]) + (reds[2] + reds[3]));
  half4 h0, l0, h1, l1;
  #pragma unroll
  for (int j = 0; j < 4; j++) {
    float p0 = e[j] * inv;
    f16 h = (f16)p0;  h0[j] = h;  l0[j] = (f16)((p0 - (float)h) * LO_SCALE);
    float p1 = e[j + 4] * inv;
    f16 g = (f16)p1;  h1[j] = g;  l1[j] = (f16)((p1 - (float)g) * LO_SCALE);
  }
  *(half4*)&pr[4 * t]            = h0;
  *(half4*)&pr[2048 + 4 * t]     = l0;
  *(half4*)&pr[1024 + 4 * t]     = h1;
  *(half4*)&pr[2048 + 1024 + 4 * t] = l1;
}

// oh/ol[c][r] = fp16 hi / scaled-lo split of in[r][c]; f32 [R][C], batch z.
__global__ __launch_bounds__(256)
void transpose_split(const float* __restrict__ in, f16* __restrict__ oh,
                     f16* __restrict__ ol, int R, int C) {
  __shared__ float tile[32][33];
  const size_t z = blockIdx.z;
  in += z * (size_t)R * C;
  oh += z * (size_t)R * C;
  ol += z * (size_t)R * C;
  const int c0 = blockIdx.x * 32;
  const int r0 = blockIdx.y * 32;
  const int tx = threadIdx.x & 31;
  const int ty = threadIdx.x >> 5;
  #pragma unroll
  for (int i = 0; i < 4; i++)
    tile[ty + i * 8][tx] = in[(size_t)(r0 + ty + i * 8) * C + c0 + tx];
  __syncthreads();
  #pragma unroll
  for (int i = 0; i < 4; i++) {
    const float v = tile[tx][ty + i * 8];
    const size_t idx = (size_t)(c0 + ty + i * 8) * R + r0 + tx;
    f16 h = (f16)v;
    oh[idx] = h;
    ol[idx] = (f16)((v - (float)h) * LO_SCALE);
  }
}

__global__ __launch_bounds__(256)
void convert_split(const float* __restrict__ in, f16* __restrict__ oh,
                   f16* __restrict__ ol, size_t n) {
  size_t i = ((size_t)blockIdx.x * blockDim.x + threadIdx.x) * 4;
  const size_t stride = (size_t)gridDim.x * blockDim.x * 4;
  for (; i < n; i += stride) {
    float4 v = *(const float4*)&in[i];
    half4 h, l;
    h[0] = (f16)v.x; l[0] = (f16)((v.x - (float)h[0]) * LO_SCALE);
    h[1] = (f16)v.y; l[1] = (f16)((v.y - (float)h[1]) * LO_SCALE);
    h[2] = (f16)v.z; l[2] = (f16)((v.z - (float)h[2]) * LO_SCALE);
    h[3] = (f16)v.w; l[3] = (f16)((v.w - (float)h[3]) * LO_SCALE);
    *(half4*)&oh[i] = h;
    *(half4*)&ol[i] = l;
  }
}

extern "C" void kernel_launch(void* const* d_in, const int* in_sizes, int n_in,
                              void* d_out, int out_size, void* d_ws, size_t ws_size,
                              hipStream_t stream) {
  (void)in_sizes; (void)n_in; (void)out_size; (void)ws_size;
  constexpr int B = 4, N = 2048, D = 1024, ITERS = 10;
  const float* x  = (const float*)d_in[0];
  const float* Wq = (const float*)d_in[1];
  const float* Wk = (const float*)d_in[2];
  float* out = (float*)d_out;

  const size_t MB = 1u << 20;
  char* ws = (char*)d_ws;
  f16* xh    = (f16*)(ws +   0 * MB);
  f16* xl    = (f16*)(ws +  16 * MB);
  f16* xTh   = (f16*)(ws +  32 * MB);
  f16* xTl   = (f16*)(ws +  48 * MB);
  f16* kth   = (f16*)(ws +  64 * MB);
  f16* ktl   = (f16*)(ws +  80 * MB);
  f16* yh    = (f16*)(ws +  96 * MB);   // K hi during prep
  f16* yl    = (f16*)(ws + 112 * MB);   // K lo during prep
  f16* wkh   = (f16*)(ws + 128 * MB);
  f16* wkl   = (f16*)(ws + 130 * MB);
  f16* wqth  = (f16*)(ws + 132 * MB);
  f16* wqtl  = (f16*)(ws + 134 * MB);
  float* scores = (float*)(ws + 136 * MB);

  const size_t ND  = (size_t)N * D;      // per-batch x/y stride
  const size_t NN  = (size_t)N * N;      // per-batch score stride (f32)
  const size_t NP  = (size_t)N * 4096;   // per-batch P stride (f16 units)

  // --- prep: splits + transposes ---
  convert_split<<<2048, 256, 0, stream>>>(x, xh, xl, (size_t)B * N * D);
  convert_split<<<512, 256, 0, stream>>>(Wk, wkh, wkl, (size_t)D * D);
  transpose_split<<<dim3(D / 32, N / 32, B), 256, 0, stream>>>(x, xTh, xTl, N, D);
  transpose_split<<<dim3(D / 32, D / 32, 1), 256, 0, stream>>>(Wq, wqth, wqtl, D, D);

  // K = x @ W_K^T -> yh/yl (scratch)   [M=8192, N=1024, K=1024]
  gemm3_nt<1><<<dim3(B * N / 128, D / 128, 1), 256, 0, stream>>>(
      xh, xl, D, wkh, wkl, D, nullptr, yh, yl, D, D, 0, 0, 0);
  // Ktil = K @ W_Q (NT vs W_Q^T) -> kth/ktl
  gemm3_nt<1><<<dim3(B * N / 128, D / 128, 1), 256, 0, stream>>>(
      yh, yl, D, wqth, wqtl, D, nullptr, kth, ktl, D, D, 0, 0, 0);

  // --- 10 iterations ---
  for (int i = 0; i < ITERS; i++) {
    const f16* bh = i ? yh : xh;
    const f16* bl = i ? yl : xl;

    // scores[b] = Ktil[b] @ y[b]^T   [2048 x 2048, K=1024] f32
    gemm3_nt<0><<<dim3(N / 128, N / 128, B), 256, 0, stream>>>(
        kth, ktl, D, bh, bl, D, scores, nullptr, nullptr, N, D, ND, ND, NN);

    softmax_split<<<dim3(B * N), 256, 0, stream>>>(scores);

    // y[b] = P[b] @ x[b] (NT vs xT)   [2048 x 1024, K=2048]
    const f16* Ph = (const f16*)scores;
    const f16* Pl = Ph + 2048;
    if (i < ITERS - 1)
      gemm3_nt<1><<<dim3(N / 128, D / 128, B), 256, 0, stream>>>(
          Ph, Pl, 4096, xTh, xTl, N, nullptr, yh, yl, D, N, NP, ND, ND);
    else
      gemm3_nt<0><<<dim3(N / 128, D / 128, B), 256, 0, stream>>>(
          Ph, Pl, 4096, xTh, xTl, N, out, nullptr, nullptr, D, N, NP, ND, ND);
  }
}

// Round 13
// 3073.441 us; speedup vs baseline: 1.1743x; 1.1743x over previous
//
#include <hip/hip_runtime.h>
#include <stdint.h>

// ImplicitQueryAttention: y <- softmax((x W_K^T) W_Q y^T) x, 10 iters.
// Ktil = (x W_K^T) W_Q is iteration-invariant -> precompute once.
// Per iter: scores = Ktil @ y^T (NT), row-softmax, y = P @ x (NT vs x^T).
//
// PRECISION (r4 6.1 bf16 -> r11 0.64 plain fp16-split -> r12 0.0645 PASS):
// scaled-lo split (lo' = (v-hi)*2^11, always fp16-normal) + separate
// correction accumulator; result = accM + accC*2^-11. Do not change.
//
// R13: T2 both-sides XOR swizzle (rule #21). Row stride is 128 B so bank =
// f(byte-in-row) only; fragment reads put lanes 0-15 at rows R..R+15, SAME
// col -> 16-way conflict (2.5e7 cycles/dispatch, ~23% of GEMM time).
// Fix: stage via inverse-swizzled GLOBAL source (linear LDS dest, required
// by global_load_lds), read at col ks ^ ((row&7)<<3). Bit-exact layout
// permutation; 16-way -> 2-way (free).

#define DEVI __device__ __forceinline__

typedef _Float16 f16;
typedef __attribute__((ext_vector_type(8))) _Float16 half8;
typedef __attribute__((ext_vector_type(4))) _Float16 half4;
typedef __attribute__((ext_vector_type(4))) float f32x4;

#define LO_SCALE 2048.0f          // 2^11
#define LO_INV   4.8828125e-4f    // 2^-11, exact

DEVI void async_ld16(void* lds, const void* g) {
  __builtin_amdgcn_global_load_lds(
      (const __attribute__((address_space(1))) uint32_t*)g,
      (__attribute__((address_space(3))) uint32_t*)lds,
      16, 0, 0);
}

// C = (Ah + Al/2^11) @ (Bh + Bl/2^11)^T, f32 accum, 3-term split-fp16 MFMA.
// Tiles in LDS are column-XOR-swizzled: tile[r][j] holds global col
// kt + (j ^ ((r&7)<<3)). Staging achieves this by pre-swizzling the global
// source column per lane; ds_read applies the same XOR. Involution => exact.
template<int OUT>
__global__ __launch_bounds__(256)
void gemm3_nt(const f16* __restrict__ Ah, const f16* __restrict__ Al, int lda,
              const f16* __restrict__ Bh, const f16* __restrict__ Bl, int ldb,
              float* __restrict__ Cf, f16* __restrict__ Ch, f16* __restrict__ Cl,
              int ldc, int K, size_t sA, size_t sB, size_t sC)
{
  __shared__ f16 lAh[128][64];
  __shared__ f16 lAl[128][64];
  __shared__ f16 lBh[128][64];
  __shared__ f16 lBl[128][64];
  const int tid  = threadIdx.x;
  const int lane = tid & 63;
  const int wid  = tid >> 6;
  const int wr   = wid >> 1, wc = wid & 1;   // 2x2 wave grid, 64x64 each
  const int row0 = blockIdx.x * 128;
  const int col0 = blockIdx.y * 128;
  const size_t z = blockIdx.z;
  Ah += z * sA;  Al += z * sA;  Bh += z * sB;  Bl += z * sB;

  f32x4 accM[4][4];   // ah*bh
  f32x4 accC[4][4];   // ah*bl' + al'*bh  (scaled by 2^11)
  #pragma unroll
  for (int i = 0; i < 4; i++)
    #pragma unroll
    for (int j = 0; j < 4; j++) {
      accM[i][j] = f32x4{0.f, 0.f, 0.f, 0.f};
      accC[i][j] = f32x4{0.f, 0.f, 0.f, 0.f};
    }

  // Staging: lane l covers stripe row r=(l>>3), tile cols (l&7)*8..+8.
  // Inverse-swizzled source col: ((l&7) ^ (l>>3)) * 8  [r&7 == l>>3].
  const int srow = wid * 32 + (lane >> 3);
  const int scol = (((lane & 7) ^ ((lane >> 3) & 7)) * 8);
  const f16* gah = Ah + (size_t)(row0 + srow) * lda + scol;
  const f16* gal = Al + (size_t)(row0 + srow) * lda + scol;
  const f16* gbh = Bh + (size_t)(col0 + srow) * ldb + scol;
  const f16* gbl = Bl + (size_t)(col0 + srow) * ldb + scol;

  for (int kt = 0; kt < K; kt += 64) {
    __syncthreads();   // previous tile's ds_reads done before overwrite
    #pragma unroll
    for (int i = 0; i < 4; i++) {
      const size_t o = (size_t)i * 8;
      async_ld16(&lAh[wid * 32 + i * 8][0], gah + o * lda + kt);
      async_ld16(&lAl[wid * 32 + i * 8][0], gal + o * lda + kt);
      async_ld16(&lBh[wid * 32 + i * 8][0], gbh + o * ldb + kt);
      async_ld16(&lBl[wid * 32 + i * 8][0], gbl + o * ldb + kt);
    }
    __syncthreads();   // vmcnt(0) drain at barrier: tiles resident

    #pragma unroll
    for (int kk = 0; kk < 2; ++kk) {
      const int ks = kk * 32 + (lane >> 4) * 8;  // lane's k-chunk
      const int fr = lane & 15;                  // frag row/col
      const int sw = (fr & 7) << 3;              // read-side XOR (f16 units)
      const int kss = ks ^ sw;
      half8 avh[4], avl[4], bvh[4], bvl[4];
      #pragma unroll
      for (int mi = 0; mi < 4; mi++) {
        avh[mi] = *(const half8*)&lAh[wr * 64 + mi * 16 + fr][kss];
        avl[mi] = *(const half8*)&lAl[wr * 64 + mi * 16 + fr][kss];
      }
      #pragma unroll
      for (int ni = 0; ni < 4; ni++) {
        bvh[ni] = *(const half8*)&lBh[wc * 64 + ni * 16 + fr][kss];
        bvl[ni] = *(const half8*)&lBl[wc * 64 + ni * 16 + fr][kss];
      }
      #pragma unroll
      for (int mi = 0; mi < 4; mi++)
        #pragma unroll
        for (int ni = 0; ni < 4; ni++) {
          accC[mi][ni] = __builtin_amdgcn_mfma_f32_16x16x32_f16(
              avh[mi], bvl[ni], accC[mi][ni], 0, 0, 0);
          accC[mi][ni] = __builtin_amdgcn_mfma_f32_16x16x32_f16(
              avl[mi], bvh[ni], accC[mi][ni], 0, 0, 0);
          accM[mi][ni] = __builtin_amdgcn_mfma_f32_16x16x32_f16(
              avh[mi], bvh[ni], accM[mi][ni], 0, 0, 0);
        }
    }
  }

  // C/D layout: col = lane&15, row = (lane>>4)*4 + reg  [m89/m91 verified]
  const int r4 = (lane >> 4) * 4;
  const int cc = lane & 15;
  #pragma unroll
  for (int mi = 0; mi < 4; mi++) {
    #pragma unroll
    for (int ni = 0; ni < 4; ni++) {
      #pragma unroll
      for (int k = 0; k < 4; k++) {
        const int row = row0 + wr * 64 + mi * 16 + r4 + k;
        const int col = col0 + wc * 64 + ni * 16 + cc;
        const float v = accM[mi][ni][k] + accC[mi][ni][k] * LO_INV;
        const size_t idx = z * sC + (size_t)row * ldc + col;
        if constexpr (OUT == 0) {
          Cf[idx] = v;
        } else {
          f16 h = (f16)v;
          f16 l = (f16)((v - (float)h) * LO_SCALE);  // exact residual, scaled
          Ch[idx] = h;
          Cl[idx] = l;
        }
      }
    }
  }
}

// One 256-thread block per 2048-f32 score row. In-place: row's 8KB becomes
// [2048 fp16 P_hi | 2048 fp16 P_lo']. Loads complete (data-dep) before the
// reduction barriers; stores after them -> no intra-row hazard.
__global__ __launch_bounds__(256)
void softmax_split(float* __restrict__ s) {
  const size_t row = blockIdx.x;
  float* sr = s + row * 2048;
  f16* pr = (f16*)sr;
  const int t = threadIdx.x;
  float4 v0 = *(const float4*)&sr[4 * t];
  float4 v1 = *(const float4*)&sr[4 * t + 1024];
  float m = fmaxf(fmaxf(fmaxf(v0.x, v0.y), fmaxf(v0.z, v0.w)),
                  fmaxf(fmaxf(v1.x, v1.y), fmaxf(v1.z, v1.w)));
  #pragma unroll
  for (int o = 32; o; o >>= 1) m = fmaxf(m, __shfl_xor(m, o));
  __shared__ float redm[4], reds[4];
  if ((t & 63) == 0) redm[t >> 6] = m;
  __syncthreads();
  m = fmaxf(fmaxf(redm[0], redm[1]), fmaxf(redm[2], redm[3]));
  float e[8];
  e[0] = expf(v0.x - m); e[1] = expf(v0.y - m);
  e[2] = expf(v0.z - m); e[3] = expf(v0.w - m);
  e[4] = expf(v1.x - m); e[5] = expf(v1.y - m);
  e[6] = expf(v1.z - m); e[7] = expf(v1.w - m);
  float sum = ((e[0] + e[1]) + (e[2] + e[3])) + ((e[4] + e[5]) + (e[6] + e[7]));
  #pragma unroll
  for (int o = 32; o; o >>= 1) sum += __shfl_xor(sum, o);
  if ((t & 63) == 0) reds[t >> 6] = sum;
  __syncthreads();
  const float inv = 1.f / ((reds[0] + reds[1]) + (reds[2] + reds[3]));
  half4 h0, l0, h1, l1;
  #pragma unroll
  for (int j = 0; j < 4; j++) {
    float p0 = e[j] * inv;
    f16 h = (f16)p0;  h0[j] = h;  l0[j] = (f16)((p0 - (float)h) * LO_SCALE);
    float p1 = e[j + 4] * inv;
    f16 g = (f16)p1;  h1[j] = g;  l1[j] = (f16)((p1 - (float)g) * LO_SCALE);
  }
  *(half4*)&pr[4 * t]            = h0;
  *(half4*)&pr[2048 + 4 * t]     = l0;
  *(half4*)&pr[1024 + 4 * t]     = h1;
  *(half4*)&pr[2048 + 1024 + 4 * t] = l1;
}

// oh/ol[c][r] = fp16 hi / scaled-lo split of in[r][c]; f32 [R][C], batch z.
__global__ __launch_bounds__(256)
void transpose_split(const float* __restrict__ in, f16* __restrict__ oh,
                     f16* __restrict__ ol, int R, int C) {
  __shared__ float tile[32][33];
  const size_t z = blockIdx.z;
  in += z * (size_t)R * C;
  oh += z * (size_t)R * C;
  ol += z * (size_t)R * C;
  const int c0 = blockIdx.x * 32;
  const int r0 = blockIdx.y * 32;
  const int tx = threadIdx.x & 31;
  const int ty = threadIdx.x >> 5;
  #pragma unroll
  for (int i = 0; i < 4; i++)
    tile[ty + i * 8][tx] = in[(size_t)(r0 + ty + i * 8) * C + c0 + tx];
  __syncthreads();
  #pragma unroll
  for (int i = 0; i < 4; i++) {
    const float v = tile[tx][ty + i * 8];
    const size_t idx = (size_t)(c0 + ty + i * 8) * R + r0 + tx;
    f16 h = (f16)v;
    oh[idx] = h;
    ol[idx] = (f16)((v - (float)h) * LO_SCALE);
  }
}

__global__ __launch_bounds__(256)
void convert_split(const float* __restrict__ in, f16* __restrict__ oh,
                   f16* __restrict__ ol, size_t n) {
  size_t i = ((size_t)blockIdx.x * blockDim.x + threadIdx.x) * 4;
  const size_t stride = (size_t)gridDim.x * blockDim.x * 4;
  for (; i < n; i += stride) {
    float4 v = *(const float4*)&in[i];
    half4 h, l;
    h[0] = (f16)v.x; l[0] = (f16)((v.x - (float)h[0]) * LO_SCALE);
    h[1] = (f16)v.y; l[1] = (f16)((v.y - (float)h[1]) * LO_SCALE);
    h[2] = (f16)v.z; l[2] = (f16)((v.z - (float)h[2]) * LO_SCALE);
    h[3] = (f16)v.w; l[3] = (f16)((v.w - (float)h[3]) * LO_SCALE);
    *(half4*)&oh[i] = h;
    *(half4*)&ol[i] = l;
  }
}

extern "C" void kernel_launch(void* const* d_in, const int* in_sizes, int n_in,
                              void* d_out, int out_size, void* d_ws, size_t ws_size,
                              hipStream_t stream) {
  (void)in_sizes; (void)n_in; (void)out_size; (void)ws_size;
  constexpr int B = 4, N = 2048, D = 1024, ITERS = 10;
  const float* x  = (const float*)d_in[0];
  const float* Wq = (const float*)d_in[1];
  const float* Wk = (const float*)d_in[2];
  float* out = (float*)d_out;

  const size_t MB = 1u << 20;
  char* ws = (char*)d_ws;
  f16* xh    = (f16*)(ws +   0 * MB);
  f16* xl    = (f16*)(ws +  16 * MB);
  f16* xTh   = (f16*)(ws +  32 * MB);
  f16* xTl   = (f16*)(ws +  48 * MB);
  f16* kth   = (f16*)(ws +  64 * MB);
  f16* ktl   = (f16*)(ws +  80 * MB);
  f16* yh    = (f16*)(ws +  96 * MB);   // K hi during prep
  f16* yl    = (f16*)(ws + 112 * MB);   // K lo during prep
  f16* wkh   = (f16*)(ws + 128 * MB);
  f16* wkl   = (f16*)(ws + 130 * MB);
  f16* wqth  = (f16*)(ws + 132 * MB);
  f16* wqtl  = (f16*)(ws + 134 * MB);
  float* scores = (float*)(ws + 136 * MB);

  const size_t ND  = (size_t)N * D;      // per-batch x/y stride
  const size_t NN  = (size_t)N * N;      // per-batch score stride (f32)
  const size_t NP  = (size_t)N * 4096;   // per-batch P stride (f16 units)

  // --- prep: splits + transposes ---
  convert_split<<<2048, 256, 0, stream>>>(x, xh, xl, (size_t)B * N * D);
  convert_split<<<512, 256, 0, stream>>>(Wk, wkh, wkl, (size_t)D * D);
  transpose_split<<<dim3(D / 32, N / 32, B), 256, 0, stream>>>(x, xTh, xTl, N, D);
  transpose_split<<<dim3(D / 32, D / 32, 1), 256, 0, stream>>>(Wq, wqth, wqtl, D, D);

  // K = x @ W_K^T -> yh/yl (scratch)   [M=8192, N=1024, K=1024]
  gemm3_nt<1><<<dim3(B * N / 128, D / 128, 1), 256, 0, stream>>>(
      xh, xl, D, wkh, wkl, D, nullptr, yh, yl, D, D, 0, 0, 0);
  // Ktil = K @ W_Q (NT vs W_Q^T) -> kth/ktl
  gemm3_nt<1><<<dim3(B * N / 128, D / 128, 1), 256, 0, stream>>>(
      yh, yl, D, wqth, wqtl, D, nullptr, kth, ktl, D, D, 0, 0, 0);

  // --- 10 iterations ---
  for (int i = 0; i < ITERS; i++) {
    const f16* bh = i ? yh : xh;
    const f16* bl = i ? yl : xl;

    // scores[b] = Ktil[b] @ y[b]^T   [2048 x 2048, K=1024] f32
    gemm3_nt<0><<<dim3(N / 128, N / 128, B), 256, 0, stream>>>(
        kth, ktl, D, bh, bl, D, scores, nullptr, nullptr, N, D, ND, ND, NN);

    softmax_split<<<dim3(B * N), 256, 0, stream>>>(scores);

    // y[b] = P[b] @ x[b] (NT vs xT)   [2048 x 1024, K=2048]
    const f16* Ph = (const f16*)scores;
    const f16* Pl = Ph + 2048;
    if (i < ITERS - 1)
      gemm3_nt<1><<<dim3(N / 128, D / 128, B), 256, 0, stream>>>(
          Ph, Pl, 4096, xTh, xTl, N, nullptr, yh, yl, D, N, NP, ND, ND);
    else
      gemm3_nt<0><<<dim3(N / 128, D / 128, B), 256, 0, stream>>>(
          Ph, Pl, 4096, xTh, xTl, N, out, nullptr, nullptr, D, N, NP, ND, ND);
  }
}